// Round 3
// baseline (414.020 us; speedup 1.0000x reference)
//
#include <hip/hip_runtime.h>
#include <stdint.h>

#define M_DIM 8192
#define N_DIM 4096
#define K_DIM 4096
#define BM 256
#define BN 128
#define BKS 64                    // K-slab bytes (i8) per pipeline stage
#define NSLAB (K_DIM / BKS)       // 64 slabs
#define A_SLOT (BM * BKS)         // 16 KB
#define B_SLOT (BN * BKS)         // 8 KB

typedef int i32x4 __attribute__((ext_vector_type(4)));

__device__ __forceinline__ void async_copy16(const void* g, void* l) {
    __builtin_amdgcn_global_load_lds(
        (const __attribute__((address_space(1))) void*)g,
        (__attribute__((address_space(3))) void*)l, 16, 0, 0);
}

// ---- pass 1: per-block partial sums of |w| (deterministic, no atomics) ----
__global__ __launch_bounds__(256) void abssum_partial(const float4* __restrict__ w,
                                                      double* __restrict__ partials) {
    const int lane = threadIdx.x & 63;
    const int wave = threadIdx.x >> 6;
    int base = blockIdx.x * 4096 + threadIdx.x;
    float s = 0.f;
    #pragma unroll
    for (int i = 0; i < 16; i++) {
        float4 v = w[base + i * 256];
        s += fabsf(v.x) + fabsf(v.y) + fabsf(v.z) + fabsf(v.w);
    }
    double d = (double)s;
    #pragma unroll
    for (int off = 32; off > 0; off >>= 1) d += __shfl_down(d, off, 64);
    __shared__ double wsum[4];
    if (lane == 0) wsum[wave] = d;
    __syncthreads();
    if (threadIdx.x == 0)
        partials[blockIdx.x] = (wsum[0] + wsum[1]) + (wsum[2] + wsum[3]);
}

// ---- pass 2: reduce 1024 partials -> gamma ----
__global__ __launch_bounds__(256) void gamma_reduce(const double* __restrict__ partials,
                                                    float* __restrict__ gamma_out) {
    const int lane = threadIdx.x & 63;
    const int wave = threadIdx.x >> 6;
    double d = partials[threadIdx.x] + partials[threadIdx.x + 256] +
               partials[threadIdx.x + 512] + partials[threadIdx.x + 768];
    #pragma unroll
    for (int off = 32; off > 0; off >>= 1) d += __shfl_down(d, off, 64);
    __shared__ double wsum[4];
    if (lane == 0) wsum[wave] = d;
    __syncthreads();
    if (threadIdx.x == 0) {
        double total = (wsum[0] + wsum[1]) + (wsum[2] + wsum[3]);
        float g = (float)(total * (1.0 / 16777216.0));  // mean |w|
        gamma_out[0] = fmaxf(g, 1e-8f);
    }
}

// ---- pass 3: quantize weight to ternary i8 ----
__global__ __launch_bounds__(256) void wquant(const float4* __restrict__ w,
                                              char4* __restrict__ qw,
                                              const float* __restrict__ gamma_p, int n4) {
    float gamma = gamma_p[0];
    int i = blockIdx.x * blockDim.x + threadIdx.x;
    if (i >= n4) return;
    float4 v = w[i];
    char4 o;
    o.x = (signed char)fminf(fmaxf(rintf(v.x / gamma), -1.f), 1.f);
    o.y = (signed char)fminf(fmaxf(rintf(v.y / gamma), -1.f), 1.f);
    o.z = (signed char)fminf(fmaxf(rintf(v.z / gamma), -1.f), 1.f);
    o.w = (signed char)fminf(fmaxf(rintf(v.w / gamma), -1.f), 1.f);
    qw[i] = o;
}

// ---- pass 4: per-row absmax + quantize x to i8 (register-resident) ----
__global__ __launch_bounds__(256) void xquant(const float4* __restrict__ x,
                                              char4* __restrict__ xq,
                                              float* __restrict__ xscale) {
    const int row = blockIdx.x;
    const int lane = threadIdx.x & 63;
    const int wave = threadIdx.x >> 6;
    const float4* xr = x + (size_t)row * (K_DIM / 4);
    float4 v[4];
    float m = 0.f;
    #pragma unroll
    for (int i = 0; i < 4; i++) {
        v[i] = xr[threadIdx.x + i * 256];
        m = fmaxf(m, fmaxf(fmaxf(fabsf(v[i].x), fabsf(v[i].y)),
                           fmaxf(fabsf(v[i].z), fabsf(v[i].w))));
    }
    #pragma unroll
    for (int off = 32; off > 0; off >>= 1) m = fmaxf(m, __shfl_down(m, off, 64));
    __shared__ float wmax[4];
    if (lane == 0) wmax[wave] = m;
    __syncthreads();
    const float mx = fmaxf(fmaxf(wmax[0], wmax[1]), fmaxf(wmax[2], wmax[3]));
    const float scale = fmaxf(mx * (1.f / 127.f), 1e-30f);
    const float inv = 1.f / scale;
    if (threadIdx.x == 0) xscale[row] = scale;
    char4* oq = xq + (size_t)row * (K_DIM / 4);
    #pragma unroll
    for (int i = 0; i < 4; i++) {
        char4 o;
        o.x = (signed char)fminf(fmaxf(rintf(v[i].x * inv), -127.f), 127.f);
        o.y = (signed char)fminf(fmaxf(rintf(v[i].y * inv), -127.f), 127.f);
        o.z = (signed char)fminf(fmaxf(rintf(v[i].z * inv), -127.f), 127.f);
        o.w = (signed char)fminf(fmaxf(rintf(v[i].w * inv), -127.f), 127.f);
        oq[threadIdx.x + i * 256] = o;
    }
}

// ---- pass 5: C[M,N] = scale[m] * (Xq[M,K] @ Qw[N,K]^T)_i32 + bias ----
//
// 256x128 tile, 512 threads / 8 waves (4M x 2N), each wave a 64x64 output
// (4x4 frags of mfma_i32_16x16x64_i8, 64 acc VGPRs). LDS ring-2 ping-pong:
// A 2x16 KB + B 2x8 KB = 48 KB -> TWO blocks co-resident per CU
// (__launch_bounds__(512,4) caps regs at 128). Rationale (R2 post-mortem):
// the 128 KB / 1-block-per-CU designs expose every phase bubble, the
// prologue fill and the epilogue store (~10 us/block) with nothing else
// resident; all three prior structures pinned at 36-40% MfmaUtil. With 2
// blocks/CU the foreign block's MFMA phase hides this block's read window,
// barrier slack, vmcnt drain, and epilogue (m114 wave-level overlap — the
// mechanism that made R0's naive loop match R1's pipeline).
//
// Per-slab cadence (R1's proven fine interleave, one phase per slab now
// that the wave tile is 16 MFMA): stage slab t+1 issue-early -> 8
// ds_read_b128 -> setprio(1) 16 MFMA setprio(0) -> vmcnt(0) -> raw
// s_barrier. Ring-2 makes the boundary a drain, but the co-resident block
// hides the residue (loads were issued a full slab earlier).
//
// Swizzle (both-sides involution, carried from R0-R2 which all passed):
// phys 16B-chunk p = c ^ ((row>>1)&3); applied on the global SOURCE of
// global_load_lds (LDS dest linear as HW forces) and on the ds_read side.
__global__ __launch_bounds__(512, 4) void gemm_kernel(
    const char* __restrict__ xq,       // [M,K] i8
    const char* __restrict__ qw,       // [N,K] i8 ternary
    const float* __restrict__ xscale,  // [M]
    const float* __restrict__ bias,    // [N]
    float* __restrict__ out)           // [M,N] fp32
{
    __shared__ __align__(16) char As[2][A_SLOT];   // 32 KB
    __shared__ __align__(16) char Bs[2][B_SLOT];   // 16 KB

    const int tid  = threadIdx.x;
    const int wave = tid >> 6;
    const int lane = tid & 63;
    const int wm   = (wave >> 1) * 64;    // 0,64,128,192
    const int wn   = (wave & 1) * 64;     // 0,64
    const int lm   = lane & 15;
    const int q4   = lane >> 4;           // logical 16B k-chunk 0..3

    const int bm = blockIdx.y * BM;
    const int bn = blockIdx.x * BN;

    // Staging (per slab per wave: 2 A rounds + 1 B round, 1 KB each).
    // Round = 16 rows x 64 B; lane l -> row base + (l>>2), phys chunk l&3,
    // source chunk swizzled: csw = (l&3) ^ ((row>>1)&3) = (l&3) ^ ((l>>3)&3).
    const int rsub = lane >> 2;                         // 0..15
    const int csw  = (lane & 3) ^ ((lane >> 3) & 3);
    const char* gA[2];
    int ldsOffA[2];
    #pragma unroll
    for (int j = 0; j < 2; j++) {
        const int r = wave * 32 + j * 16 + rsub;
        gA[j] = xq + (size_t)(bm + r) * K_DIM + csw * 16;
        ldsOffA[j] = (wave * 32 + j * 16) * BKS;
    }
    const char* gB0 = qw + (size_t)(bn + wave * 16 + rsub) * K_DIM + csw * 16;
    const int ldsOffB = wave * 16 * BKS;

    i32x4 acc[4][4];
    #pragma unroll
    for (int i = 0; i < 4; i++)
        #pragma unroll
        for (int j = 0; j < 4; j++) acc[i][j] = (i32x4){0, 0, 0, 0};

    // read-side swizzled chunk offset: phys = q4 ^ ((row>>1)&3), row&15 == lm
    const int pc = (q4 ^ ((lm >> 1) & 3)) * 16;

    auto stage_slab = [&](int ts, int slot) {
        async_copy16(gA[0] + (size_t)ts * BKS, &As[slot][ldsOffA[0]]);
        async_copy16(gA[1] + (size_t)ts * BKS, &As[slot][ldsOffA[1]]);
        async_copy16(gB0   + (size_t)ts * BKS, &Bs[slot][ldsOffB]);
    };

    auto compute_slab = [&](const char* Ab, const char* Bb) {
        i32x4 a[4], b[4];
        #pragma unroll
        for (int ni = 0; ni < 4; ni++)
            b[ni] = *(const i32x4*)(Bb + (wn + ni * 16 + lm) * BKS + pc);
        #pragma unroll
        for (int mi = 0; mi < 4; mi++)
            a[mi] = *(const i32x4*)(Ab + (wm + mi * 16 + lm) * BKS + pc);
        __builtin_amdgcn_s_setprio(1);
        #pragma unroll
        for (int mi = 0; mi < 4; mi++)
            #pragma unroll
            for (int ni = 0; ni < 4; ni++)
                acc[mi][ni] = __builtin_amdgcn_mfma_i32_16x16x64_i8(
                    a[mi], b[ni], acc[mi][ni], 0, 0, 0);
        __builtin_amdgcn_s_setprio(0);
    };

    // ---- prologue: stage slab 0 ----
    stage_slab(0, 0);
    asm volatile("s_waitcnt vmcnt(0)" ::: "memory");
    __builtin_amdgcn_s_barrier();

    // ---- main loop: ping-pong, stage issue-early, drain+barrier/slab ----
    for (int t = 0; t < NSLAB - 2; t += 2) {
        stage_slab(t + 1, 1);
        compute_slab(As[0], Bs[0]);
        asm volatile("s_waitcnt vmcnt(0)" ::: "memory");
        __builtin_amdgcn_s_barrier();

        stage_slab(t + 2, 0);
        compute_slab(As[1], Bs[1]);
        asm volatile("s_waitcnt vmcnt(0)" ::: "memory");
        __builtin_amdgcn_s_barrier();
    }
    // ---- tail: t = 62, 63 ----
    stage_slab(NSLAB - 1, 1);
    compute_slab(As[0], Bs[0]);
    asm volatile("s_waitcnt vmcnt(0)" ::: "memory");
    __builtin_amdgcn_s_barrier();
    compute_slab(As[1], Bs[1]);

    // epilogue: C/D layout col=lane&15, row=quad*4+reg (shape-determined)
    float bl[4];
    #pragma unroll
    for (int ni = 0; ni < 4; ni++) bl[ni] = bias[bn + wn + ni * 16 + lm];

    #pragma unroll
    for (int mi = 0; mi < 4; mi++) {
        #pragma unroll
        for (int r = 0; r < 4; r++) {
            const int grow = bm + wm + mi * 16 + q4 * 4 + r;
            const float sc = xscale[grow];
            float* orow = out + (size_t)grow * N_DIM + bn + wn;
            #pragma unroll
            for (int ni = 0; ni < 4; ni++)
                orow[ni * 16 + lm] = sc * (float)acc[mi][ni][r] + bl[ni];
        }
    }
}

extern "C" void kernel_launch(void* const* d_in, const int* in_sizes, int n_in,
                              void* d_out, int out_size, void* d_ws, size_t ws_size,
                              hipStream_t stream) {
    const float* x    = (const float*)d_in[0];   // [4,2048,4096] = [8192,4096]
    const float* w    = (const float*)d_in[1];   // [4096,4096]
    const float* bias = (const float*)d_in[2];   // [4096]
    float* out = (float*)d_out;

    char* ws = (char*)d_ws;
    char*   xq       = ws;                                        // 32 MB
    char*   qw       = ws + (size_t)M_DIM * K_DIM;                // 16 MB
    float*  xscale   = (float*)(qw + (size_t)N_DIM * K_DIM);      // 32 KB
    double* partials = (double*)(xscale + M_DIM);                 // 8 KB
    float*  gamma_p  = (float*)(partials + 1024);                 // 4 B

    const int wn4 = (N_DIM * K_DIM) / 4;

    abssum_partial<<<1024, 256, 0, stream>>>((const float4*)w, partials);
    gamma_reduce<<<1, 256, 0, stream>>>(partials, gamma_p);
    wquant<<<(wn4 + 255) / 256, 256, 0, stream>>>((const float4*)w, (char4*)qw, gamma_p, wn4);
    xquant<<<M_DIM, 256, 0, stream>>>((const float4*)x, (char4*)xq, xscale);

    dim3 grid(N_DIM / BN, M_DIM / BM);   // (32, 32) = 1024 blocks = 4/CU
    gemm_kernel<<<grid, 512, 0, stream>>>(xq, qw, xscale, bias, out);
}

// Round 4
// 410.456 us; speedup vs baseline: 1.0087x; 1.0087x over previous
//
#include <hip/hip_runtime.h>
#include <stdint.h>

#define M_DIM 8192
#define N_DIM 4096
#define K_DIM 4096
#define BM 256
#define BN 128
#define BKS 64                    // K-slab bytes (i8) per pipeline stage
#define NSLAB (K_DIM / BKS)       // 64 slabs
#define A_SLOT (BM * BKS)         // 16 KB
#define B_SLOT (BN * BKS)         // 8 KB

typedef int i32x4 __attribute__((ext_vector_type(4)));

__device__ __forceinline__ void async_copy16(const void* g, void* l) {
    __builtin_amdgcn_global_load_lds(
        (const __attribute__((address_space(1))) void*)g,
        (__attribute__((address_space(3))) void*)l, 16, 0, 0);
}

// ---- fused pass 1: blocks [0,1024) do |w| partial sums; blocks [1024,9216)
// ---- do per-row x absmax + i8 quantize (xquant is gamma-independent).
__global__ __launch_bounds__(256) void prep_kernel(
    const float4* __restrict__ w,
    const float4* __restrict__ x,
    double* __restrict__ partials,
    char4* __restrict__ xq,
    float* __restrict__ xscale)
{
    const int lane = threadIdx.x & 63;
    const int wave = threadIdx.x >> 6;

    if (blockIdx.x < 1024) {
        // ---- abssum partial (unchanged reduction order) ----
        int base = blockIdx.x * 4096 + threadIdx.x;
        float s = 0.f;
        #pragma unroll
        for (int i = 0; i < 16; i++) {
            float4 v = w[base + i * 256];
            s += fabsf(v.x) + fabsf(v.y) + fabsf(v.z) + fabsf(v.w);
        }
        double d = (double)s;
        #pragma unroll
        for (int off = 32; off > 0; off >>= 1) d += __shfl_down(d, off, 64);
        __shared__ double wsum[4];
        if (lane == 0) wsum[wave] = d;
        __syncthreads();
        if (threadIdx.x == 0)
            partials[blockIdx.x] = (wsum[0] + wsum[1]) + (wsum[2] + wsum[3]);
    } else {
        // ---- xquant (unchanged numerics) ----
        const int row = blockIdx.x - 1024;
        const float4* xr = x + (size_t)row * (K_DIM / 4);
        float4 v[4];
        float m = 0.f;
        #pragma unroll
        for (int i = 0; i < 4; i++) {
            v[i] = xr[threadIdx.x + i * 256];
            m = fmaxf(m, fmaxf(fmaxf(fabsf(v[i].x), fabsf(v[i].y)),
                               fmaxf(fabsf(v[i].z), fabsf(v[i].w))));
        }
        #pragma unroll
        for (int off = 32; off > 0; off >>= 1) m = fmaxf(m, __shfl_down(m, off, 64));
        __shared__ float wmax[4];
        if (lane == 0) wmax[wave] = m;
        __syncthreads();
        const float mx = fmaxf(fmaxf(wmax[0], wmax[1]), fmaxf(wmax[2], wmax[3]));
        const float scale = fmaxf(mx * (1.f / 127.f), 1e-30f);
        const float inv = 1.f / scale;
        if (threadIdx.x == 0) xscale[row] = scale;
        char4* oq = xq + (size_t)row * (K_DIM / 4);
        #pragma unroll
        for (int i = 0; i < 4; i++) {
            char4 o;
            o.x = (signed char)fminf(fmaxf(rintf(v[i].x * inv), -127.f), 127.f);
            o.y = (signed char)fminf(fmaxf(rintf(v[i].y * inv), -127.f), 127.f);
            o.z = (signed char)fminf(fmaxf(rintf(v[i].z * inv), -127.f), 127.f);
            o.w = (signed char)fminf(fmaxf(rintf(v[i].w * inv), -127.f), 127.f);
            oq[threadIdx.x + i * 256] = o;
        }
    }
}

// ---- fused pass 2: per-block gamma reduction (bitwise-identical order to
// ---- the old gamma_reduce) + ternary weight quantize, 16 float4/thread.
__global__ __launch_bounds__(256) void wquant_kernel(
    const double* __restrict__ partials,
    const float4* __restrict__ w,
    char4* __restrict__ qw)
{
    const int lane = threadIdx.x & 63;
    const int wave = threadIdx.x >> 6;
    double d = partials[threadIdx.x] + partials[threadIdx.x + 256] +
               partials[threadIdx.x + 512] + partials[threadIdx.x + 768];
    #pragma unroll
    for (int off = 32; off > 0; off >>= 1) d += __shfl_down(d, off, 64);
    __shared__ double wsum[4];
    if (lane == 0) wsum[wave] = d;
    __shared__ float gsh;
    __syncthreads();
    if (threadIdx.x == 0) {
        double total = (wsum[0] + wsum[1]) + (wsum[2] + wsum[3]);
        gsh = fmaxf((float)(total * (1.0 / 16777216.0)), 1e-8f);
    }
    __syncthreads();
    const float gamma = gsh;

    int base = blockIdx.x * 4096 + threadIdx.x;
    #pragma unroll
    for (int j = 0; j < 16; j++) {
        float4 v = w[base + j * 256];
        char4 o;
        o.x = (signed char)fminf(fmaxf(rintf(v.x / gamma), -1.f), 1.f);
        o.y = (signed char)fminf(fmaxf(rintf(v.y / gamma), -1.f), 1.f);
        o.z = (signed char)fminf(fmaxf(rintf(v.z / gamma), -1.f), 1.f);
        o.w = (signed char)fminf(fmaxf(rintf(v.w / gamma), -1.f), 1.f);
        qw[base + j * 256] = o;
    }
}

// ---- pass 3: C[M,N] = scale[m] * (Xq[M,K] @ Qw[N,K]^T)_i32 + bias ----
//
// R4 geometry: 256x128 tile, 256 threads / 4 waves (2M x 2N), each wave a
// 128x64 output (8x4 frags of mfma_i32_16x16x64_i8, 128 acc VGPRs).
// Rationale (R3 post-mortem): LDS port traffic is a co-limiter with the
// MFMA pipe. Wave tile 128x64 -> 1/87 B/op (vs 1/64 at 64x64): per-CU LDS
// traffic 18 MB (~70 us floor) instead of 23 MB (~95 us). Ring-3 LDS
// (3 x 24 KB = 72 KB) keeps TWO blocks co-resident per CU (144 KB) so the
// counted-vmcnt pipeline AND cross-block overlap both apply -- the first
// structure in this session with all three mechanisms at once.
//
// Per-slab cadence: stage slab t+2 (6 x global_load_lds) -> 12 ds_read_b128
// -> setprio(1) 32 MFMA setprio(0) -> s_waitcnt vmcnt(6) -> s_barrier.
// Sync ledger:
//  - RAW: at slab-t boundary, outstanding = slabs t+1,t+2 (12 loads);
//    vmcnt(6) retires slab t+1, barrier publishes all waves' staging.
//  - WAR: stage(t+2) writes slot (t+2)%3 = (t-1)%3, last read during slab
//    t-1, which completed before the slab t-1 barrier < issue time.
//  - Tail: t=62 waits vmcnt(0) for slab 63; t=63 computes, no stage.
//  - Unroll x3 -> all slot indices compile-time.
// Swizzle (both-sides involution, proven R0-R3): phys 16B-chunk
// p = c ^ ((row>>1)&3) on the global SOURCE of global_load_lds (LDS dest
// linear as HW forces) and identically on the ds_read side.
__global__ __launch_bounds__(256, 2) void gemm_kernel(
    const char* __restrict__ xq,       // [M,K] i8
    const char* __restrict__ qw,       // [N,K] i8 ternary
    const float* __restrict__ xscale,  // [M]
    const float* __restrict__ bias,    // [N]
    float* __restrict__ out)           // [M,N] fp32
{
    __shared__ __align__(16) char As[3][A_SLOT];   // 48 KB
    __shared__ __align__(16) char Bs[3][B_SLOT];   // 24 KB

    const int tid  = threadIdx.x;
    const int wave = tid >> 6;
    const int lane = tid & 63;
    const int wm   = (wave >> 1) * 128;   // 0,128
    const int wn   = (wave & 1) * 64;     // 0,64
    const int lm   = lane & 15;
    const int q4   = lane >> 4;           // logical 16B k-chunk 0..3

    const int bm = blockIdx.y * BM;
    const int bn = blockIdx.x * BN;

    // Staging: per slab per wave, 4 A rounds + 2 B rounds (1 KB = 16 rows
    // x 64 B each). Lane l -> row base + (l>>2), phys chunk l&3, source
    // chunk swizzled: csw = (l&3) ^ ((row>>1)&3) = (l&3) ^ ((l>>3)&3).
    const int rsub = lane >> 2;                         // 0..15
    const int csw  = (lane & 3) ^ ((lane >> 3) & 3);
    const char* gA[4];
    int ldsOffA[4];
    #pragma unroll
    for (int j = 0; j < 4; j++) {
        const int r = wave * 64 + j * 16 + rsub;
        gA[j] = xq + (size_t)(bm + r) * K_DIM + csw * 16;
        ldsOffA[j] = (wave * 64 + j * 16) * BKS;
    }
    const char* gB[2];
    int ldsOffB[2];
    #pragma unroll
    for (int j = 0; j < 2; j++) {
        const int r = wave * 32 + j * 16 + rsub;
        gB[j] = qw + (size_t)(bn + r) * K_DIM + csw * 16;
        ldsOffB[j] = (wave * 32 + j * 16) * BKS;
    }

    i32x4 acc[8][4];
    #pragma unroll
    for (int i = 0; i < 8; i++)
        #pragma unroll
        for (int j = 0; j < 4; j++) acc[i][j] = (i32x4){0, 0, 0, 0};

    // read-side swizzled chunk offset: phys = q4 ^ ((row>>1)&3), row&15 == lm
    const int pc = (q4 ^ ((lm >> 1) & 3)) * 16;

    auto stage_slab = [&](int ts, int slot) {
        #pragma unroll
        for (int j = 0; j < 4; j++)
            async_copy16(gA[j] + (size_t)ts * BKS, &As[slot][ldsOffA[j]]);
        #pragma unroll
        for (int j = 0; j < 2; j++)
            async_copy16(gB[j] + (size_t)ts * BKS, &Bs[slot][ldsOffB[j]]);
    };

    auto compute_slab = [&](const char* Ab, const char* Bb) {
        i32x4 b[4], a[8];
        #pragma unroll
        for (int ni = 0; ni < 4; ni++)
            b[ni] = *(const i32x4*)(Bb + (wn + ni * 16 + lm) * BKS + pc);
        #pragma unroll
        for (int mi = 0; mi < 8; mi++)
            a[mi] = *(const i32x4*)(Ab + (wm + mi * 16 + lm) * BKS + pc);
        __builtin_amdgcn_s_setprio(1);
        #pragma unroll
        for (int mi = 0; mi < 8; mi++)
            #pragma unroll
            for (int ni = 0; ni < 4; ni++)
                acc[mi][ni] = __builtin_amdgcn_mfma_i32_16x16x64_i8(
                    a[mi], b[ni], acc[mi][ni], 0, 0, 0);
        __builtin_amdgcn_s_setprio(0);
    };

    // ---- prologue: stage slabs 0,1 ----
    stage_slab(0, 0);
    stage_slab(1, 1);
    asm volatile("s_waitcnt vmcnt(6)" ::: "memory");   // slab 0 resident
    __builtin_amdgcn_s_barrier();

    // ---- main loop: t = 0..59 (unrolled x3, static ring slots) ----
    for (int tb = 0; tb < 60; tb += 3) {
        #pragma unroll
        for (int u = 0; u < 3; u++) {
            stage_slab(tb + u + 2, (u + 2) % 3);
            compute_slab(As[u], Bs[u]);
            asm volatile("s_waitcnt vmcnt(6)" ::: "memory");
            __builtin_amdgcn_s_barrier();
        }
    }

    // ---- tail: t = 60..63 ----
    stage_slab(62, 2);                 // 62 % 3 == 2
    compute_slab(As[0], Bs[0]);        // t=60
    asm volatile("s_waitcnt vmcnt(6)" ::: "memory");
    __builtin_amdgcn_s_barrier();

    stage_slab(63, 0);                 // 63 % 3 == 0
    compute_slab(As[1], Bs[1]);        // t=61
    asm volatile("s_waitcnt vmcnt(6)" ::: "memory");
    __builtin_amdgcn_s_barrier();

    compute_slab(As[2], Bs[2]);        // t=62
    asm volatile("s_waitcnt vmcnt(0)" ::: "memory");
    __builtin_amdgcn_s_barrier();

    compute_slab(As[0], Bs[0]);        // t=63

    // epilogue: C/D layout col=lane&15, row=quad*4+reg (shape-determined)
    float bl[4];
    #pragma unroll
    for (int ni = 0; ni < 4; ni++) bl[ni] = bias[bn + wn + ni * 16 + lm];

    #pragma unroll
    for (int mi = 0; mi < 8; mi++) {
        #pragma unroll
        for (int r = 0; r < 4; r++) {
            const int grow = bm + wm + mi * 16 + q4 * 4 + r;
            const float sc = xscale[grow];
            float* orow = out + (size_t)grow * N_DIM + bn + wn;
            #pragma unroll
            for (int ni = 0; ni < 4; ni++)
                orow[ni * 16 + lm] = sc * (float)acc[mi][ni][r] + bl[ni];
        }
    }
}

extern "C" void kernel_launch(void* const* d_in, const int* in_sizes, int n_in,
                              void* d_out, int out_size, void* d_ws, size_t ws_size,
                              hipStream_t stream) {
    const float* x    = (const float*)d_in[0];   // [4,2048,4096] = [8192,4096]
    const float* w    = (const float*)d_in[1];   // [4096,4096]
    const float* bias = (const float*)d_in[2];   // [4096]
    float* out = (float*)d_out;

    char* ws = (char*)d_ws;
    char*   xq       = ws;                                        // 32 MB
    char*   qw       = ws + (size_t)M_DIM * K_DIM;                // 16 MB
    float*  xscale   = (float*)(qw + (size_t)N_DIM * K_DIM);      // 32 KB
    double* partials = (double*)(xscale + M_DIM);                 // 8 KB
    float*  gamma_p  = (float*)(partials + 1024);                 // 4 B
    (void)gamma_p;

    prep_kernel<<<1024 + M_DIM, 256, 0, stream>>>(
        (const float4*)w, (const float4*)x, partials, (char4*)xq, xscale);
    wquant_kernel<<<1024, 256, 0, stream>>>(partials, (const float4*)w, (char4*)qw);

    dim3 grid(N_DIM / BN, M_DIM / BM);   // (32, 32) = 1024 blocks
    gemm_kernel<<<grid, 256, 0, stream>>>(xq, qw, xscale, bias, out);
}

// Round 5
// 405.662 us; speedup vs baseline: 1.0206x; 1.0118x over previous
//
#include <hip/hip_runtime.h>
#include <stdint.h>

#define M_DIM 8192
#define N_DIM 4096
#define K_DIM 4096
#define BM 256
#define BN 256
#define BKS 64                    // K-slab bytes (i8) per pipeline stage
#define NSLAB (K_DIM / BKS)       // 64 slabs
#define SLOT_BYTES (256 * BKS)    // 16 KB per matrix per ring slot

typedef int i32x4 __attribute__((ext_vector_type(4)));

__device__ __forceinline__ void async_copy16(const void* g, void* l) {
    __builtin_amdgcn_global_load_lds(
        (const __attribute__((address_space(1))) void*)g,
        (__attribute__((address_space(3))) void*)l, 16, 0, 0);
}

// ---- fused pass 1: blocks [0,1024) do |w| partial sums; blocks [1024,9216)
// ---- do per-row x absmax + i8 quantize (xquant is gamma-independent).
__global__ __launch_bounds__(256) void prep_kernel(
    const float4* __restrict__ w,
    const float4* __restrict__ x,
    double* __restrict__ partials,
    char4* __restrict__ xq,
    float* __restrict__ xscale)
{
    const int lane = threadIdx.x & 63;
    const int wave = threadIdx.x >> 6;

    if (blockIdx.x < 1024) {
        int base = blockIdx.x * 4096 + threadIdx.x;
        float s = 0.f;
        #pragma unroll
        for (int i = 0; i < 16; i++) {
            float4 v = w[base + i * 256];
            s += fabsf(v.x) + fabsf(v.y) + fabsf(v.z) + fabsf(v.w);
        }
        double d = (double)s;
        #pragma unroll
        for (int off = 32; off > 0; off >>= 1) d += __shfl_down(d, off, 64);
        __shared__ double wsum[4];
        if (lane == 0) wsum[wave] = d;
        __syncthreads();
        if (threadIdx.x == 0)
            partials[blockIdx.x] = (wsum[0] + wsum[1]) + (wsum[2] + wsum[3]);
    } else {
        const int row = blockIdx.x - 1024;
        const float4* xr = x + (size_t)row * (K_DIM / 4);
        float4 v[4];
        float m = 0.f;
        #pragma unroll
        for (int i = 0; i < 4; i++) {
            v[i] = xr[threadIdx.x + i * 256];
            m = fmaxf(m, fmaxf(fmaxf(fabsf(v[i].x), fabsf(v[i].y)),
                               fmaxf(fabsf(v[i].z), fabsf(v[i].w))));
        }
        #pragma unroll
        for (int off = 32; off > 0; off >>= 1) m = fmaxf(m, __shfl_down(m, off, 64));
        __shared__ float wmax[4];
        if (lane == 0) wmax[wave] = m;
        __syncthreads();
        const float mx = fmaxf(fmaxf(wmax[0], wmax[1]), fmaxf(wmax[2], wmax[3]));
        const float scale = fmaxf(mx * (1.f / 127.f), 1e-30f);
        const float inv = 1.f / scale;
        if (threadIdx.x == 0) xscale[row] = scale;
        char4* oq = xq + (size_t)row * (K_DIM / 4);
        #pragma unroll
        for (int i = 0; i < 4; i++) {
            char4 o;
            o.x = (signed char)fminf(fmaxf(rintf(v[i].x * inv), -127.f), 127.f);
            o.y = (signed char)fminf(fmaxf(rintf(v[i].y * inv), -127.f), 127.f);
            o.z = (signed char)fminf(fmaxf(rintf(v[i].z * inv), -127.f), 127.f);
            o.w = (signed char)fminf(fmaxf(rintf(v[i].w * inv), -127.f), 127.f);
            oq[threadIdx.x + i * 256] = o;
        }
    }
}

// ---- fused pass 2: gamma reduce (bitwise-identical order) + w quantize ----
__global__ __launch_bounds__(256) void wquant_kernel(
    const double* __restrict__ partials,
    const float4* __restrict__ w,
    char4* __restrict__ qw)
{
    const int lane = threadIdx.x & 63;
    const int wave = threadIdx.x >> 6;
    double d = partials[threadIdx.x] + partials[threadIdx.x + 256] +
               partials[threadIdx.x + 512] + partials[threadIdx.x + 768];
    #pragma unroll
    for (int off = 32; off > 0; off >>= 1) d += __shfl_down(d, off, 64);
    __shared__ double wsum[4];
    if (lane == 0) wsum[wave] = d;
    __shared__ float gsh;
    __syncthreads();
    if (threadIdx.x == 0) {
        double total = (wsum[0] + wsum[1]) + (wsum[2] + wsum[3]);
        gsh = fmaxf((float)(total * (1.0 / 16777216.0)), 1e-8f);
    }
    __syncthreads();
    const float gamma = gsh;

    int base = blockIdx.x * 4096 + threadIdx.x;
    #pragma unroll
    for (int j = 0; j < 16; j++) {
        float4 v = w[base + j * 256];
        char4 o;
        o.x = (signed char)fminf(fmaxf(rintf(v.x / gamma), -1.f), 1.f);
        o.y = (signed char)fminf(fmaxf(rintf(v.y / gamma), -1.f), 1.f);
        o.z = (signed char)fminf(fmaxf(rintf(v.z / gamma), -1.f), 1.f);
        o.w = (signed char)fminf(fmaxf(rintf(v.w / gamma), -1.f), 1.f);
        qw[base + j * 256] = o;
    }
}

// ---- pass 3: C[M,N] = scale[m] * (Xq[M,K] @ Qw[N,K]^T)_i32 + bias ----
//
// R5 = R1 (best measured: 147 us) + the m201 template's ISA-level phase
// pins, nothing else changed. R1-R4 post-mortems: LDS-read window and MFMA
// window serialize EXACTLY (sum of floors == measured in all 5 variants).
// The template hides reads via the pinned phase shape:
//   [ds_read issue][stage][sched_barrier(0)]
//   [s_barrier]                      <- read latency absorbed by arrival
//   [asm lgkmcnt(0)][sched_barrier(0)]  <- rule #18: stop MFMA hoisting /
//   [setprio(1) 16 MFMA setprio(0)]     read sinking by the compiler
//   [s_barrier]
// Staging split 2+2 across the two phases (m196 fine interleave).
//
// Ring/sync ledger (identical to R1, re-verified):
//  - ring-4 slots; compute slab t from slot t&3; stage slab t+3 into slot
//    (t+3)&3 = (t-1)&3, whose last reads retired at each wave's phase-B
//    lgkmcnt(0) BEFORE the slab t-1 boundary barrier -> WAR-safe.
//  - end-of-slab-t vmcnt(8): leaves newest 8 loads = slabs t+2,t+3;
//    retires t+1; boundary barrier publishes -> RAW-safe.
//  - tail drains 8 -> 4 -> 0 (t=61,62 boundaries).
//  - swizzle (both-sides involution, 4 rounds verified): phys 16B-chunk
//    p = c ^ ((row>>1)&3) on gload source and ds_read side; conflicts = 0.
__global__ __launch_bounds__(512, 2) void gemm_kernel(
    const char* __restrict__ xq,       // [M,K] i8
    const char* __restrict__ qw,       // [N,K] i8 ternary
    const float* __restrict__ xscale,  // [M]
    const float* __restrict__ bias,    // [N]
    float* __restrict__ out)           // [M,N] fp32
{
    __shared__ __align__(16) char As[4][SLOT_BYTES];   // 64 KB
    __shared__ __align__(16) char Bs[4][SLOT_BYTES];   // 64 KB

    const int tid  = threadIdx.x;
    const int wave = tid >> 6;
    const int lane = tid & 63;
    const int wm   = (wave >> 2) * 128;   // 0 or 128
    const int wn   = (wave & 3) * 64;     // 0,64,128,192
    const int lm   = lane & 15;
    const int q4   = lane >> 4;           // logical 16B k-chunk 0..3

    const int bm = blockIdx.y * BM;
    const int bn = blockIdx.x * BN;

    // Staging geometry (R1): wave w covers rows [w*32, w*32+32) of A and B,
    // two 16-row rounds j=0,1 (1 KB gload each). Lane l -> row base+(l>>2),
    // phys chunk l&3; source chunk swizzled.
    const int rsub = lane >> 2;                         // 0..15
    const int csw  = (lane & 3) ^ ((lane >> 3) & 3);
    const char* gA[2];
    const char* gB[2];
    int ldsOff[2];
    #pragma unroll
    for (int j = 0; j < 2; j++) {
        const int r = wave * 32 + j * 16 + rsub;
        gA[j] = xq + (size_t)(bm + r) * K_DIM + csw * 16;
        gB[j] = qw + (size_t)(bn + r) * K_DIM + csw * 16;
        ldsOff[j] = (wave * 32 + j * 16) * BKS;
    }

    i32x4 acc[8][4];
    #pragma unroll
    for (int i = 0; i < 8; i++)
        #pragma unroll
        for (int j = 0; j < 4; j++) acc[i][j] = (i32x4){0, 0, 0, 0};

    // read-side swizzled chunk offset
    const int pc = (q4 ^ ((lm >> 1) & 3)) * 16;

    // one slab = two pinned phases; staging 2 loads per phase
    auto do_slab = [&](const char* Ab, const char* Bb, int ts, int slot,
                       bool do_stage) {
        // ---------- phase A: mi 0..3 ----------
        i32x4 b[4], a[4];
        #pragma unroll
        for (int ni = 0; ni < 4; ni++)
            b[ni] = *(const i32x4*)(Bb + (wn + ni * 16 + lm) * BKS + pc);
        #pragma unroll
        for (int mi = 0; mi < 4; mi++)
            a[mi] = *(const i32x4*)(Ab + (wm + mi * 16 + lm) * BKS + pc);
        if (do_stage) {
            async_copy16(gA[0] + (size_t)ts * BKS, &As[slot][ldsOff[0]]);
            async_copy16(gB[0] + (size_t)ts * BKS, &Bs[slot][ldsOff[0]]);
        }
        __builtin_amdgcn_sched_barrier(0);
        __builtin_amdgcn_s_barrier();
        asm volatile("s_waitcnt lgkmcnt(0)" ::: "memory");
        __builtin_amdgcn_sched_barrier(0);
        __builtin_amdgcn_s_setprio(1);
        #pragma unroll
        for (int mi = 0; mi < 4; mi++)
            #pragma unroll
            for (int ni = 0; ni < 4; ni++)
                acc[mi][ni] = __builtin_amdgcn_mfma_i32_16x16x64_i8(
                    a[mi], b[ni], acc[mi][ni], 0, 0, 0);
        __builtin_amdgcn_s_setprio(0);
        __builtin_amdgcn_s_barrier();

        // ---------- phase B: mi 4..7 (b reused) ----------
        i32x4 a2[4];
        #pragma unroll
        for (int mi = 0; mi < 4; mi++)
            a2[mi] = *(const i32x4*)(Ab + (wm + (4 + mi) * 16 + lm) * BKS + pc);
        if (do_stage) {
            async_copy16(gA[1] + (size_t)ts * BKS, &As[slot][ldsOff[1]]);
            async_copy16(gB[1] + (size_t)ts * BKS, &Bs[slot][ldsOff[1]]);
        }
        __builtin_amdgcn_sched_barrier(0);
        __builtin_amdgcn_s_barrier();
        asm volatile("s_waitcnt lgkmcnt(0)" ::: "memory");
        __builtin_amdgcn_sched_barrier(0);
        __builtin_amdgcn_s_setprio(1);
        #pragma unroll
        for (int mi = 0; mi < 4; mi++)
            #pragma unroll
            for (int ni = 0; ni < 4; ni++)
                acc[4 + mi][ni] = __builtin_amdgcn_mfma_i32_16x16x64_i8(
                    a2[mi], b[ni], acc[4 + mi][ni], 0, 0, 0);
        __builtin_amdgcn_s_setprio(0);
    };

    // ---- prologue: stage slabs 0,1,2 (12 loads/thread) ----
    #pragma unroll
    for (int s = 0; s < 3; s++) {
        #pragma unroll
        for (int j = 0; j < 2; j++) {
            async_copy16(gA[j] + (size_t)s * BKS, &As[s][ldsOff[j]]);
            async_copy16(gB[j] + (size_t)s * BKS, &Bs[s][ldsOff[j]]);
        }
    }
    asm volatile("s_waitcnt vmcnt(8)" ::: "memory");   // slab 0 resident
    __builtin_amdgcn_s_barrier();

    // ---- main loop: t = 0..59 (unrolled x4, static ring slots) ----
    for (int tb = 0; tb < 60; tb += 4) {
        #pragma unroll
        for (int u = 0; u < 4; u++) {
            do_slab(As[u], Bs[u], tb + u + 3, (u + 3) & 3, true);
            asm volatile("s_waitcnt vmcnt(8)" ::: "memory");
            __builtin_amdgcn_s_barrier();
        }
    }

    // ---- peeled t = 60 (stages slab 63), then drain 8 -> 4 -> 0 ----
    do_slab(As[0], Bs[0], 63, 3, true);
    asm volatile("s_waitcnt vmcnt(8)" ::: "memory");
    __builtin_amdgcn_s_barrier();

    do_slab(As[1], Bs[1], 0, 0, false);                // t = 61
    asm volatile("s_waitcnt vmcnt(4)" ::: "memory");
    __builtin_amdgcn_s_barrier();

    do_slab(As[2], Bs[2], 0, 0, false);                // t = 62
    asm volatile("s_waitcnt vmcnt(0)" ::: "memory");
    __builtin_amdgcn_s_barrier();

    do_slab(As[3], Bs[3], 0, 0, false);                // t = 63

    // epilogue: C/D layout col=lane&15, row=quad*4+reg (shape-determined)
    float bl[4];
    #pragma unroll
    for (int ni = 0; ni < 4; ni++) bl[ni] = bias[bn + wn + ni * 16 + lm];

    #pragma unroll
    for (int mi = 0; mi < 8; mi++) {
        #pragma unroll
        for (int r = 0; r < 4; r++) {
            const int grow = bm + wm + mi * 16 + q4 * 4 + r;
            const float sc = xscale[grow];
            float* orow = out + (size_t)grow * N_DIM + bn + wn;
            #pragma unroll
            for (int ni = 0; ni < 4; ni++)
                orow[ni * 16 + lm] = sc * (float)acc[mi][ni][r] + bl[ni];
        }
    }
}

extern "C" void kernel_launch(void* const* d_in, const int* in_sizes, int n_in,
                              void* d_out, int out_size, void* d_ws, size_t ws_size,
                              hipStream_t stream) {
    const float* x    = (const float*)d_in[0];   // [4,2048,4096] = [8192,4096]
    const float* w    = (const float*)d_in[1];   // [4096,4096]
    const float* bias = (const float*)d_in[2];   // [4096]
    float* out = (float*)d_out;

    char* ws = (char*)d_ws;
    char*   xq       = ws;                                        // 32 MB
    char*   qw       = ws + (size_t)M_DIM * K_DIM;                // 16 MB
    float*  xscale   = (float*)(qw + (size_t)N_DIM * K_DIM);      // 32 KB
    double* partials = (double*)(xscale + M_DIM);                 // 8 KB

    prep_kernel<<<1024 + M_DIM, 256, 0, stream>>>(
        (const float4*)w, (const float4*)x, partials, (char4*)xq, xscale);
    wquant_kernel<<<1024, 256, 0, stream>>>(partials, (const float4*)w, (char4*)qw);

    dim3 grid(N_DIM / BN, M_DIM / BM);   // (16, 32) = 512 blocks
    gemm_kernel<<<grid, 512, 0, stream>>>(xq, qw, xscale, bias, out);
}